// Round 18
// baseline (280.790 us; speedup 1.0000x reference)
//
#include <hip/hip_runtime.h>

#define NN 400000
#define NE 400000

typedef __attribute__((ext_vector_type(4))) float f32x4;
typedef __attribute__((ext_vector_type(8))) short s16x8;
typedef unsigned short ushort_t;

__device__ __forceinline__ ushort_t f2bf(float f) {
    union { float f; unsigned int u; } c;
    c.f = f;
    unsigned int u = c.u;
    u = u + 0x7fffu + ((u >> 16) & 1u);
    return (ushort_t)(u >> 16);
}
__device__ __forceinline__ float bf2f(ushort_t v) {
    union { unsigned int u; float f; } c;
    c.u = ((unsigned int)v) << 16;
    return c.f;
}

// --- merged prep: blocks 0..255 W->bf16; block 256 attB table; block 257 int64 detect ---
__global__ void k_prep(const float* __restrict__ W, ushort_t* __restrict__ wbf,
                       const float* __restrict__ att, ushort_t* __restrict__ attB,
                       const int* __restrict__ ei_raw, int* __restrict__ flag) {
    if (blockIdx.x < 256) {
        const int i = blockIdx.x * 256 + threadIdx.x;
        wbf[i] = f2bf(W[i]);
    } else if (blockIdx.x == 256) {
        const int t = threadIdx.x;          // 256
        const int ks = t >> 6, lane = t & 63;
        const int col = lane & 15, kg = lane >> 4;
        const int jb = ks * 32 + kg * 8;
        s16x8 pk;
#pragma unroll
        for (int m = 0; m < 8; m++) {
            float v = 0.f;
            if (col < 4)      v = att[col * 256 + jb + m];
            else if (col < 8) v = att[(col - 4) * 256 + 128 + jb + m];
            pk[m] = (short)f2bf(v);
        }
        *(s16x8*)(attB + (size_t)(ks * 64 + lane) * 8) = pk;
    } else {
        // int64 detect: 64 parallel lane loads + ballot (wave 0 only)
        if (threadIdx.x < 64) {
            const int v = ei_raw[2 * threadIdx.x + 1];
            const unsigned long long b = __ballot(v != 0);
            if (threadIdx.x == 0) flag[0] = (b == 0ULL) ? 1 : 0;
        }
    }
}

// --- fused u,v + x->bf16, MFMA version (r15-proven) ---
__global__ __launch_bounds__(256) void k_uv_mfma(
    const float* __restrict__ x, const ushort_t* __restrict__ attB,
    ushort_t* __restrict__ xbf, float* __restrict__ uv) {
    const int lane = threadIdx.x & 63;
    const int wv = threadIdx.x >> 6;     // 4 waves/block
    const int kg = lane >> 4;

    s16x8 bfr[4];
#pragma unroll
    for (int ks = 0; ks < 4; ks++)
        bfr[ks] = *(const s16x8*)(attB + (size_t)(ks * 64 + lane) * 8);

    const f32x4 zero = {0.f, 0.f, 0.f, 0.f};
    const int ntiles = NN / 64;

#pragma unroll 1
    for (int tile = blockIdx.x; tile < ntiles; tile += gridDim.x) {
        const int n = tile * 64 + wv * 16 + (lane & 15);
        const float* xr = x + (size_t)n * 128 + kg * 8;
        ushort_t* xw = xbf + (size_t)n * 128 + kg * 8;

        s16x8 afr[4];
#pragma unroll
        for (int ks = 0; ks < 4; ks++) {
            const f32x4 a0 = *(const f32x4*)(xr + ks * 32);
            const f32x4 a1 = *(const f32x4*)(xr + ks * 32 + 4);
            s16x8 pk;
#pragma unroll
            for (int m = 0; m < 4; m++) { pk[m] = (short)f2bf(a0[m]); pk[4 + m] = (short)f2bf(a1[m]); }
            afr[ks] = pk;
            *(s16x8*)(xw + ks * 32) = pk;    // xbf output (same bytes as A-frag)
        }
        f32x4 c = zero;
#pragma unroll
        for (int ks = 0; ks < 4; ks++)
            c = __builtin_amdgcn_mfma_f32_16x16x32_bf16(afr[ks], bfr[ks], c, 0, 0, 0);

        const int colc = lane & 15;
        if (colc < 8) {
#pragma unroll
            for (int r = 0; r < 4; r++) {
                const int nn = tile * 64 + wv * 16 + kg * 4 + r;
                uv[(size_t)nn * 8 + colc] = c[r];
            }
        }
    }
}

// --- per-edge (fused idx-convert): leaky_relu -> head softmax -> p=exp, atomic
//     denom; also emits ei32 ---
__global__ void k_edge(const int* __restrict__ ei_raw, const int* __restrict__ flag,
                       const float* __restrict__ uv, float* __restrict__ p,
                       float* __restrict__ denom, int* __restrict__ ei32) {
    const int e = blockIdx.x * 256 + threadIdx.x;
    if (e >= NE) return;
    const int f = flag[0];
    const int row = f ? ei_raw[2 * e] : ei_raw[e];
    const int col = f ? ei_raw[2 * (NE + e)] : ei_raw[NE + e];
    ei32[e] = row;
    ei32[NE + e] = col;
    const f32x4 u = *(const f32x4*)(uv + (size_t)row * 8);
    const f32x4 v = *(const f32x4*)(uv + (size_t)col * 8 + 4);
    float s[4];
    float mx = -1e30f;
#pragma unroll
    for (int h = 0; h < 4; h++) {
        float t = u[h] + v[h];
        t = t > 0.f ? t : 0.01f * t;
        s[h] = t;
        mx = fmaxf(mx, t);
    }
    float ex[4], sum = 0.f;
#pragma unroll
    for (int h = 0; h < 4; h++) { ex[h] = __expf(s[h] - mx); sum += ex[h]; }
    const float inv = 1.f / sum;
    f32x4 pv;
#pragma unroll
    for (int h = 0; h < 4; h++) pv[h] = __expf(ex[h] * inv);
    *(f32x4*)(p + (size_t)e * 4) = pv;
#pragma unroll
    for (int h = 0; h < 4; h++) atomicAdd(denom + (size_t)row * 4 + h, pv[h]);
}

// --- alpha4[e] = p[e,:] / denom[row[e],:] ---
__global__ void k_alpha(const int* __restrict__ ei, const float* __restrict__ p,
                        const float* __restrict__ denom, float* __restrict__ alpha4) {
    const int e = blockIdx.x * 256 + threadIdx.x;
    if (e >= NE) return;
    const int row = ei[e];
    const f32x4 pv = *(const f32x4*)(p + (size_t)e * 4);
    const f32x4 dv = *(const f32x4*)(denom + (size_t)row * 4);
    *(f32x4*)(alpha4 + (size_t)e * 4) = pv / dv;
}

// --- persistent head-split GEMM, v8 (proven best: 118-122 µs, plain stores).
//     16 waves, grid=256. Bsm 128KB + Asm 2x16KB = 160KB. Tile=64 edges,
//     double-buffered A via global_load_lds, 1 barrier/tile, per-lane alpha
//     load + bpermute shuffles. Closed doors (measured): alpha plane-loads
//     (v9/v10: hipcc sinks VMEM to first use -> vmcnt stalls), operand swap
//     (v12: A/B operand layouts not interchangeable), nt-stores (r16: WRITE
//     +63MB, no FETCH gain), B-in-VGPR (v5-v7: allocator remats >64 regs). ---
__global__ __launch_bounds__(1024, 4) void k_gemm(
    const ushort_t* __restrict__ xbf, const int* __restrict__ ei,
    const float* __restrict__ alpha4, const ushort_t* __restrict__ wbf,
    const float* __restrict__ bias, float* __restrict__ out)
{
    __shared__ __align__(16) ushort_t Bsm[128 * 512];   // 128KB [icol][k], swz ((icol&15)<<4)
    __shared__ __align__(16) ushort_t Asm[2][64 * 128]; // 2x16KB [e][k],  swz ((e&15)<<4)

    const int tid = threadIdx.x;
    const int lane = tid & 63;
    const int w = tid >> 6;       // 0..15
    const int eg = w & 1;         // edge group: rows eg*32..+32
    const int cg = w >> 1;        // col group:  cols cg*16..+16

    // stage W once (r10-proven conflict-free map)
    {
        const int icol = tid & 127, seg = tid >> 7;
        const ushort_t* src = wbf + icol * 512 + seg * 64;
#pragma unroll
        for (int m = 0; m < 8; m++) {
            const s16x8 v = *(const s16x8*)(src + m * 8);
            const int byte = icol * 1024 + ((seg * 128 + m * 16) ^ ((icol & 15) << 4));
            *(s16x8*)((char*)Bsm + byte) = v;
        }
    }
    const int icol = cg * 16 + (lane & 15);
    const float bias_r = bias[icol];

    const f32x4 zero = {0.f, 0.f, 0.f, 0.f};
    const int ntiles = NE / 64;
    const int stride = gridDim.x;

    auto STAGE = [&](int tt, int b) {
        const int rr = w * 4 + (lane >> 4);
        const int col = ei[NE + tt * 64 + rr];
        const int c = (lane & 15) ^ (rr & 15);
        const ushort_t* src = xbf + (size_t)col * 128 + c * 8;
        __builtin_amdgcn_global_load_lds(
            (const __attribute__((address_space(1))) unsigned int*)src,
            (__attribute__((address_space(3))) unsigned int*)((char*)Asm[b] + w * 1024),
            16, 0, 0);
    };

    int t = blockIdx.x;
    int cur = 0;
    if (t < ntiles) STAGE(t, 0);

#pragma unroll 1
    for (; t < ntiles; t += stride) {
        __syncthreads();
        const int tn = t + stride;
        if (tn < ntiles) STAGE(tn, cur ^ 1);

        const f32x4 alp = *(const f32x4*)(alpha4 + (size_t)(t * 64 + eg * 32 + (lane & 31)) * 4);

        s16x8 af[2][4];
#pragma unroll
        for (int eb = 0; eb < 2; eb++) {
            const int rr = eg * 32 + eb * 16 + (lane & 15);
#pragma unroll
            for (int ks = 0; ks < 4; ks++) {
                const int byte = rr * 256 + ((ks * 64 + (lane >> 4) * 16) ^ ((rr & 15) << 4));
                af[eb][ks] = *(const s16x8*)((const char*)Asm[cur] + byte);
            }
        }

        f32x4 fin[2];
        fin[0] = zero; fin[1] = zero;

#pragma unroll
        for (int h = 0; h < 4; h++) {
            s16x8 bfr[4];
#pragma unroll
            for (int ks = 0; ks < 4; ks++) {
                const int byte = icol * 1024 +
                    ((h * 256 + ks * 64 + (lane >> 4) * 16) ^ ((icol & 15) << 4));
                bfr[ks] = *(const s16x8*)((const char*)Bsm + byte);
            }
#pragma unroll
            for (int eb = 0; eb < 2; eb++) {
                f32x4 a = __builtin_amdgcn_mfma_f32_16x16x32_bf16(af[eb][0], bfr[0], zero, 0, 0, 0);
#pragma unroll
                for (int ks = 1; ks < 4; ks++)
                    a = __builtin_amdgcn_mfma_f32_16x16x32_bf16(af[eb][ks], bfr[ks], a, 0, 0, 0);
                f32x4 av;
#pragma unroll
                for (int r = 0; r < 4; r++)
                    av[r] = __shfl(alp[h], eb * 16 + (lane >> 4) * 4 + r, 64);
                fin[eb] += av * a;
            }
        }
        // epilogue: + bias + residual (plain stores)
#pragma unroll
        for (int eb = 0; eb < 2; eb++) {
#pragma unroll
            for (int r = 0; r < 4; r++) {
                const int e = t * 64 + eg * 32 + eb * 16 + (lane >> 4) * 4 + r;
                const size_t off = (size_t)e * 128 + icol;
                out[off] = fin[eb][r] + bias_r + bf2f(xbf[off]);
            }
        }
        cur ^= 1;
    }
}

extern "C" void kernel_launch(void* const* d_in, const int* in_sizes, int n_in,
                              void* d_out, int out_size, void* d_ws, size_t ws_size,
                              hipStream_t stream) {
    const float* x      = (const float*)d_in[0];
    const int*   ei_raw = (const int*)d_in[1];
    const float* att    = (const float*)d_in[2];
    const float* W      = (const float*)d_in[3];
    const float* b      = (const float*)d_in[4];
    float* out = (float*)d_out;

    char* ws = (char*)d_ws;
    float*    uv      = (float*)(ws);                     // N*8 f32   = 12.8 MB
    float*    p       = (float*)(ws + 12800000);          // E*4 f32   =  6.4 MB
    float*    denom   = (float*)(ws + 19200000);          // N*4 f32   =  6.4 MB
    float*    alpha4  = (float*)(ws + 25600000);          // E*4 f32   =  6.4 MB
    ushort_t* wbf     = (ushort_t*)(ws + 32000000);       // 128 KB
    int*      flag    = (int*)(ws + 32200000);            // 4 B
    ushort_t* attB    = (ushort_t*)(ws + 32200064);       // 4 KB
    int*      ei32    = (int*)(ws + 32210048);            // 3.2 MB
    ushort_t* xbf     = (ushort_t*)(ws + 35420224);       // N*128 bf16 = 102.4 MB

    hipMemsetAsync(denom, 0, (size_t)NN * 4 * sizeof(float), stream);
    k_prep<<<258, 256, 0, stream>>>(W, wbf, att, attB, ei_raw, flag);
    k_uv_mfma<<<2048, 256, 0, stream>>>(x, attB, xbf, uv);
    k_edge<<<(NE + 255) / 256, 256, 0, stream>>>(ei_raw, flag, uv, p, denom, ei32);
    k_alpha<<<(NE + 255) / 256, 256, 0, stream>>>(ei32, p, denom, alpha4);
    k_gemm<<<256, 1024, 0, stream>>>(xbf, ei32, alpha4, wbf, b, out);
}

// Round 19
// 267.545 us; speedup vs baseline: 1.0495x; 1.0495x over previous
//
#include <hip/hip_runtime.h>

#define NN 400000
#define NE 400000

typedef __attribute__((ext_vector_type(4))) float f32x4;
typedef __attribute__((ext_vector_type(8))) short s16x8;
typedef unsigned short ushort_t;

__device__ __forceinline__ ushort_t f2bf(float f) {
    union { float f; unsigned int u; } c;
    c.f = f;
    unsigned int u = c.u;
    u = u + 0x7fffu + ((u >> 16) & 1u);
    return (ushort_t)(u >> 16);
}
__device__ __forceinline__ float bf2f(ushort_t v) {
    union { unsigned int u; float f; } c;
    c.u = ((unsigned int)v) << 16;
    return c.f;
}

// --- merged prep: blocks 0..255 W->bf16; block 256 attB table; block 257 int64 detect ---
__global__ void k_prep(const float* __restrict__ W, ushort_t* __restrict__ wbf,
                       const float* __restrict__ att, ushort_t* __restrict__ attB,
                       const int* __restrict__ ei_raw, int* __restrict__ flag) {
    if (blockIdx.x < 256) {
        const int i = blockIdx.x * 256 + threadIdx.x;
        wbf[i] = f2bf(W[i]);
    } else if (blockIdx.x == 256) {
        const int t = threadIdx.x;          // 256
        const int ks = t >> 6, lane = t & 63;
        const int col = lane & 15, kg = lane >> 4;
        const int jb = ks * 32 + kg * 8;
        s16x8 pk;
#pragma unroll
        for (int m = 0; m < 8; m++) {
            float v = 0.f;
            if (col < 4)      v = att[col * 256 + jb + m];
            else if (col < 8) v = att[(col - 4) * 256 + 128 + jb + m];
            pk[m] = (short)f2bf(v);
        }
        *(s16x8*)(attB + (size_t)(ks * 64 + lane) * 8) = pk;
    } else {
        if (threadIdx.x < 64) {
            const int v = ei_raw[2 * threadIdx.x + 1];
            const unsigned long long b = __ballot(v != 0);
            if (threadIdx.x == 0) flag[0] = (b == 0ULL) ? 1 : 0;
        }
    }
}

// --- fused u,v + x->bf16, MFMA version + NONTEMPORAL x loads.
//     x (205MB) is read exactly once; plain loads stream it through L3 and
//     evict the xbf being written (102MB) -> k_gemm's gather missed to HBM
//     (FETCH 130MB). nt-loads keep xbf L3-resident for k_gemm. ---
__global__ __launch_bounds__(256) void k_uv_mfma(
    const float* __restrict__ x, const ushort_t* __restrict__ attB,
    ushort_t* __restrict__ xbf, float* __restrict__ uv) {
    const int lane = threadIdx.x & 63;
    const int wv = threadIdx.x >> 6;     // 4 waves/block
    const int kg = lane >> 4;

    s16x8 bfr[4];
#pragma unroll
    for (int ks = 0; ks < 4; ks++)
        bfr[ks] = *(const s16x8*)(attB + (size_t)(ks * 64 + lane) * 8);

    const f32x4 zero = {0.f, 0.f, 0.f, 0.f};
    const int ntiles = NN / 64;

#pragma unroll 1
    for (int tile = blockIdx.x; tile < ntiles; tile += gridDim.x) {
        const int n = tile * 64 + wv * 16 + (lane & 15);
        const float* xr = x + (size_t)n * 128 + kg * 8;
        ushort_t* xw = xbf + (size_t)n * 128 + kg * 8;

        s16x8 afr[4];
#pragma unroll
        for (int ks = 0; ks < 4; ks++) {
            const f32x4 a0 = __builtin_nontemporal_load((const f32x4*)(xr + ks * 32));
            const f32x4 a1 = __builtin_nontemporal_load((const f32x4*)(xr + ks * 32 + 4));
            s16x8 pk;
#pragma unroll
            for (int m = 0; m < 4; m++) { pk[m] = (short)f2bf(a0[m]); pk[4 + m] = (short)f2bf(a1[m]); }
            afr[ks] = pk;
            *(s16x8*)(xw + ks * 32) = pk;    // xbf output (same bytes as A-frag)
        }
        f32x4 c = zero;
#pragma unroll
        for (int ks = 0; ks < 4; ks++)
            c = __builtin_amdgcn_mfma_f32_16x16x32_bf16(afr[ks], bfr[ks], c, 0, 0, 0);

        const int colc = lane & 15;
        if (colc < 8) {
#pragma unroll
            for (int r = 0; r < 4; r++) {
                const int nn = tile * 64 + wv * 16 + kg * 4 + r;
                uv[(size_t)nn * 8 + colc] = c[r];
            }
        }
    }
}

// --- per-edge (fused idx-convert): leaky_relu -> head softmax -> p=exp, atomic
//     denom; also emits ei32 ---
__global__ void k_edge(const int* __restrict__ ei_raw, const int* __restrict__ flag,
                       const float* __restrict__ uv, float* __restrict__ p,
                       float* __restrict__ denom, int* __restrict__ ei32) {
    const int e = blockIdx.x * 256 + threadIdx.x;
    if (e >= NE) return;
    const int f = flag[0];
    const int row = f ? ei_raw[2 * e] : ei_raw[e];
    const int col = f ? ei_raw[2 * (NE + e)] : ei_raw[NE + e];
    ei32[e] = row;
    ei32[NE + e] = col;
    const f32x4 u = *(const f32x4*)(uv + (size_t)row * 8);
    const f32x4 v = *(const f32x4*)(uv + (size_t)col * 8 + 4);
    float s[4];
    float mx = -1e30f;
#pragma unroll
    for (int h = 0; h < 4; h++) {
        float t = u[h] + v[h];
        t = t > 0.f ? t : 0.01f * t;
        s[h] = t;
        mx = fmaxf(mx, t);
    }
    float ex[4], sum = 0.f;
#pragma unroll
    for (int h = 0; h < 4; h++) { ex[h] = __expf(s[h] - mx); sum += ex[h]; }
    const float inv = 1.f / sum;
    f32x4 pv;
#pragma unroll
    for (int h = 0; h < 4; h++) pv[h] = __expf(ex[h] * inv);
    *(f32x4*)(p + (size_t)e * 4) = pv;
#pragma unroll
    for (int h = 0; h < 4; h++) atomicAdd(denom + (size_t)row * 4 + h, pv[h]);
}

// --- alpha4[e] = p[e,:] / denom[row[e],:] ---
__global__ void k_alpha(const int* __restrict__ ei, const float* __restrict__ p,
                        const float* __restrict__ denom, float* __restrict__ alpha4) {
    const int e = blockIdx.x * 256 + threadIdx.x;
    if (e >= NE) return;
    const int row = ei[e];
    const f32x4 pv = *(const f32x4*)(p + (size_t)e * 4);
    const f32x4 dv = *(const f32x4*)(denom + (size_t)row * 4);
    *(f32x4*)(alpha4 + (size_t)e * 4) = pv / dv;
}

// --- persistent head-split GEMM, v8 + NONTEMPORAL out stores.
//     nt-out mechanism (r16 vs r18 A/B): k_gemm dur unchanged, but plain
//     stores leave 203MB dirty in L2/L3 that the NEXT replay's kernels pay
//     for (total −17 µs with nt). Closed doors (measured): alpha plane-loads
//     (v9/v10), operand swap (v12), B-in-VGPR (v5-v7). ---
__global__ __launch_bounds__(1024, 4) void k_gemm(
    const ushort_t* __restrict__ xbf, const int* __restrict__ ei,
    const float* __restrict__ alpha4, const ushort_t* __restrict__ wbf,
    const float* __restrict__ bias, float* __restrict__ out)
{
    __shared__ __align__(16) ushort_t Bsm[128 * 512];   // 128KB [icol][k], swz ((icol&15)<<4)
    __shared__ __align__(16) ushort_t Asm[2][64 * 128]; // 2x16KB [e][k],  swz ((e&15)<<4)

    const int tid = threadIdx.x;
    const int lane = tid & 63;
    const int w = tid >> 6;       // 0..15
    const int eg = w & 1;         // edge group: rows eg*32..+32
    const int cg = w >> 1;        // col group:  cols cg*16..+16

    // stage W once (r10-proven conflict-free map)
    {
        const int icol = tid & 127, seg = tid >> 7;
        const ushort_t* src = wbf + icol * 512 + seg * 64;
#pragma unroll
        for (int m = 0; m < 8; m++) {
            const s16x8 v = *(const s16x8*)(src + m * 8);
            const int byte = icol * 1024 + ((seg * 128 + m * 16) ^ ((icol & 15) << 4));
            *(s16x8*)((char*)Bsm + byte) = v;
        }
    }
    const int icol = cg * 16 + (lane & 15);
    const float bias_r = bias[icol];

    const f32x4 zero = {0.f, 0.f, 0.f, 0.f};
    const int ntiles = NE / 64;
    const int stride = gridDim.x;

    auto STAGE = [&](int tt, int b) {
        const int rr = w * 4 + (lane >> 4);
        const int col = ei[NE + tt * 64 + rr];
        const int c = (lane & 15) ^ (rr & 15);
        const ushort_t* src = xbf + (size_t)col * 128 + c * 8;
        __builtin_amdgcn_global_load_lds(
            (const __attribute__((address_space(1))) unsigned int*)src,
            (__attribute__((address_space(3))) unsigned int*)((char*)Asm[b] + w * 1024),
            16, 0, 0);
    };

    int t = blockIdx.x;
    int cur = 0;
    if (t < ntiles) STAGE(t, 0);

#pragma unroll 1
    for (; t < ntiles; t += stride) {
        __syncthreads();
        const int tn = t + stride;
        if (tn < ntiles) STAGE(tn, cur ^ 1);

        const f32x4 alp = *(const f32x4*)(alpha4 + (size_t)(t * 64 + eg * 32 + (lane & 31)) * 4);

        s16x8 af[2][4];
#pragma unroll
        for (int eb = 0; eb < 2; eb++) {
            const int rr = eg * 32 + eb * 16 + (lane & 15);
#pragma unroll
            for (int ks = 0; ks < 4; ks++) {
                const int byte = rr * 256 + ((ks * 64 + (lane >> 4) * 16) ^ ((rr & 15) << 4));
                af[eb][ks] = *(const s16x8*)((const char*)Asm[cur] + byte);
            }
        }

        f32x4 fin[2];
        fin[0] = zero; fin[1] = zero;

#pragma unroll
        for (int h = 0; h < 4; h++) {
            s16x8 bfr[4];
#pragma unroll
            for (int ks = 0; ks < 4; ks++) {
                const int byte = icol * 1024 +
                    ((h * 256 + ks * 64 + (lane >> 4) * 16) ^ ((icol & 15) << 4));
                bfr[ks] = *(const s16x8*)((const char*)Bsm + byte);
            }
#pragma unroll
            for (int eb = 0; eb < 2; eb++) {
                f32x4 a = __builtin_amdgcn_mfma_f32_16x16x32_bf16(af[eb][0], bfr[0], zero, 0, 0, 0);
#pragma unroll
                for (int ks = 1; ks < 4; ks++)
                    a = __builtin_amdgcn_mfma_f32_16x16x32_bf16(af[eb][ks], bfr[ks], a, 0, 0, 0);
                f32x4 av;
#pragma unroll
                for (int r = 0; r < 4; r++)
                    av[r] = __shfl(alp[h], eb * 16 + (lane >> 4) * 4 + r, 64);
                fin[eb] += av * a;
            }
        }
        // epilogue: + bias + residual; NONTEMPORAL out stores (write-once data)
#pragma unroll
        for (int eb = 0; eb < 2; eb++) {
#pragma unroll
            for (int r = 0; r < 4; r++) {
                const int e = t * 64 + eg * 32 + eb * 16 + (lane >> 4) * 4 + r;
                const size_t off = (size_t)e * 128 + icol;
                __builtin_nontemporal_store(fin[eb][r] + bias_r + bf2f(xbf[off]), &out[off]);
            }
        }
        cur ^= 1;
    }
}

extern "C" void kernel_launch(void* const* d_in, const int* in_sizes, int n_in,
                              void* d_out, int out_size, void* d_ws, size_t ws_size,
                              hipStream_t stream) {
    const float* x      = (const float*)d_in[0];
    const int*   ei_raw = (const int*)d_in[1];
    const float* att    = (const float*)d_in[2];
    const float* W      = (const float*)d_in[3];
    const float* b      = (const float*)d_in[4];
    float* out = (float*)d_out;

    char* ws = (char*)d_ws;
    float*    uv      = (float*)(ws);                     // N*8 f32   = 12.8 MB
    float*    p       = (float*)(ws + 12800000);          // E*4 f32   =  6.4 MB
    float*    denom   = (float*)(ws + 19200000);          // N*4 f32   =  6.4 MB
    float*    alpha4  = (float*)(ws + 25600000);          // E*4 f32   =  6.4 MB
    ushort_t* wbf     = (ushort_t*)(ws + 32000000);       // 128 KB
    int*      flag    = (int*)(ws + 32200000);            // 4 B
    ushort_t* attB    = (ushort_t*)(ws + 32200064);       // 4 KB
    int*      ei32    = (int*)(ws + 32210048);            // 3.2 MB
    ushort_t* xbf     = (ushort_t*)(ws + 35420224);       // N*128 bf16 = 102.4 MB

    hipMemsetAsync(denom, 0, (size_t)NN * 4 * sizeof(float), stream);
    k_prep<<<258, 256, 0, stream>>>(W, wbf, att, attB, ei_raw, flag);
    k_uv_mfma<<<2048, 256, 0, stream>>>(x, attB, xbf, uv);
    k_edge<<<(NE + 255) / 256, 256, 0, stream>>>(ei_raw, flag, uv, p, denom, ei32);
    k_alpha<<<(NE + 255) / 256, 256, 0, stream>>>(ei32, p, denom, alpha4);
    k_gemm<<<256, 1024, 0, stream>>>(xbf, ei32, alpha4, wbf, b, out);
}

// Round 20
// 265.766 us; speedup vs baseline: 1.0565x; 1.0067x over previous
//
#include <hip/hip_runtime.h>

#define NN 400000
#define NE 400000

typedef __attribute__((ext_vector_type(4))) float f32x4;
typedef __attribute__((ext_vector_type(8))) short s16x8;
typedef unsigned short ushort_t;

__device__ __forceinline__ ushort_t f2bf(float f) {
    union { float f; unsigned int u; } c;
    c.f = f;
    unsigned int u = c.u;
    u = u + 0x7fffu + ((u >> 16) & 1u);
    return (ushort_t)(u >> 16);
}
__device__ __forceinline__ float bf2f(ushort_t v) {
    union { unsigned int u; float f; } c;
    c.u = ((unsigned int)v) << 16;
    return c.f;
}

// --- merged prep: blocks 0..255 W->bf16; block 256 attB; block 257 int64 detect;
//     blocks 258.. zero denom (replaces hipMemsetAsync: the rocclr fill kernel
//     measured 112-117 µs/replay as the first node of each graph replay). ---
__global__ void k_prep(const float* __restrict__ W, ushort_t* __restrict__ wbf,
                       const float* __restrict__ att, ushort_t* __restrict__ attB,
                       const int* __restrict__ ei_raw, int* __restrict__ flag,
                       float* __restrict__ denom) {
    if (blockIdx.x < 256) {
        const int i = blockIdx.x * 256 + threadIdx.x;
        wbf[i] = f2bf(W[i]);
    } else if (blockIdx.x == 256) {
        const int t = threadIdx.x;          // 256
        const int ks = t >> 6, lane = t & 63;
        const int col = lane & 15, kg = lane >> 4;
        const int jb = ks * 32 + kg * 8;
        s16x8 pk;
#pragma unroll
        for (int m = 0; m < 8; m++) {
            float v = 0.f;
            if (col < 4)      v = att[col * 256 + jb + m];
            else if (col < 8) v = att[(col - 4) * 256 + 128 + jb + m];
            pk[m] = (short)f2bf(v);
        }
        *(s16x8*)(attB + (size_t)(ks * 64 + lane) * 8) = pk;
    } else if (blockIdx.x == 257) {
        if (threadIdx.x < 64) {
            const int v = ei_raw[2 * threadIdx.x + 1];
            const unsigned long long b = __ballot(v != 0);
            if (threadIdx.x == 0) flag[0] = (b == 0ULL) ? 1 : 0;
        }
    } else {
        // zero denom: NN*4 floats = 400000 f32x4 vectors, one per thread
        const int i = (blockIdx.x - 258) * 256 + threadIdx.x;
        if (i < NN) *(f32x4*)(denom + (size_t)i * 4) = (f32x4){0.f, 0.f, 0.f, 0.f};
    }
}

// --- fused u,v + x->bf16, MFMA + nt x loads (r18/19-proven) ---
__global__ __launch_bounds__(256) void k_uv_mfma(
    const float* __restrict__ x, const ushort_t* __restrict__ attB,
    ushort_t* __restrict__ xbf, float* __restrict__ uv) {
    const int lane = threadIdx.x & 63;
    const int wv = threadIdx.x >> 6;     // 4 waves/block
    const int kg = lane >> 4;

    s16x8 bfr[4];
#pragma unroll
    for (int ks = 0; ks < 4; ks++)
        bfr[ks] = *(const s16x8*)(attB + (size_t)(ks * 64 + lane) * 8);

    const f32x4 zero = {0.f, 0.f, 0.f, 0.f};
    const int ntiles = NN / 64;

#pragma unroll 1
    for (int tile = blockIdx.x; tile < ntiles; tile += gridDim.x) {
        const int n = tile * 64 + wv * 16 + (lane & 15);
        const float* xr = x + (size_t)n * 128 + kg * 8;
        ushort_t* xw = xbf + (size_t)n * 128 + kg * 8;

        s16x8 afr[4];
#pragma unroll
        for (int ks = 0; ks < 4; ks++) {
            const f32x4 a0 = __builtin_nontemporal_load((const f32x4*)(xr + ks * 32));
            const f32x4 a1 = __builtin_nontemporal_load((const f32x4*)(xr + ks * 32 + 4));
            s16x8 pk;
#pragma unroll
            for (int m = 0; m < 4; m++) { pk[m] = (short)f2bf(a0[m]); pk[4 + m] = (short)f2bf(a1[m]); }
            afr[ks] = pk;
            *(s16x8*)(xw + ks * 32) = pk;    // xbf output (same bytes as A-frag)
        }
        f32x4 c = zero;
#pragma unroll
        for (int ks = 0; ks < 4; ks++)
            c = __builtin_amdgcn_mfma_f32_16x16x32_bf16(afr[ks], bfr[ks], c, 0, 0, 0);

        const int colc = lane & 15;
        if (colc < 8) {
#pragma unroll
            for (int r = 0; r < 4; r++) {
                const int nn = tile * 64 + wv * 16 + kg * 4 + r;
                uv[(size_t)nn * 8 + colc] = c[r];
            }
        }
    }
}

// --- per-edge (fused idx-convert): leaky_relu -> head softmax -> p=exp, atomic
//     denom; also emits ei32 ---
__global__ void k_edge(const int* __restrict__ ei_raw, const int* __restrict__ flag,
                       const float* __restrict__ uv, float* __restrict__ p,
                       float* __restrict__ denom, int* __restrict__ ei32) {
    const int e = blockIdx.x * 256 + threadIdx.x;
    if (e >= NE) return;
    const int f = flag[0];
    const int row = f ? ei_raw[2 * e] : ei_raw[e];
    const int col = f ? ei_raw[2 * (NE + e)] : ei_raw[NE + e];
    ei32[e] = row;
    ei32[NE + e] = col;
    const f32x4 u = *(const f32x4*)(uv + (size_t)row * 8);
    const f32x4 v = *(const f32x4*)(uv + (size_t)col * 8 + 4);
    float s[4];
    float mx = -1e30f;
#pragma unroll
    for (int h = 0; h < 4; h++) {
        float t = u[h] + v[h];
        t = t > 0.f ? t : 0.01f * t;
        s[h] = t;
        mx = fmaxf(mx, t);
    }
    float ex[4], sum = 0.f;
#pragma unroll
    for (int h = 0; h < 4; h++) { ex[h] = __expf(s[h] - mx); sum += ex[h]; }
    const float inv = 1.f / sum;
    f32x4 pv;
#pragma unroll
    for (int h = 0; h < 4; h++) pv[h] = __expf(ex[h] * inv);
    *(f32x4*)(p + (size_t)e * 4) = pv;
#pragma unroll
    for (int h = 0; h < 4; h++) atomicAdd(denom + (size_t)row * 4 + h, pv[h]);
}

// --- alpha4[e] = p[e,:] / denom[row[e],:] ---
__global__ void k_alpha(const int* __restrict__ ei, const float* __restrict__ p,
                        const float* __restrict__ denom, float* __restrict__ alpha4) {
    const int e = blockIdx.x * 256 + threadIdx.x;
    if (e >= NE) return;
    const int row = ei[e];
    const f32x4 pv = *(const f32x4*)(p + (size_t)e * 4);
    const f32x4 dv = *(const f32x4*)(denom + (size_t)row * 4);
    *(f32x4*)(alpha4 + (size_t)e * 4) = pv / dv;
}

// --- persistent head-split GEMM, v8 + nt out stores (r18/19-proven) ---
__global__ __launch_bounds__(1024, 4) void k_gemm(
    const ushort_t* __restrict__ xbf, const int* __restrict__ ei,
    const float* __restrict__ alpha4, const ushort_t* __restrict__ wbf,
    const float* __restrict__ bias, float* __restrict__ out)
{
    __shared__ __align__(16) ushort_t Bsm[128 * 512];   // 128KB [icol][k], swz ((icol&15)<<4)
    __shared__ __align__(16) ushort_t Asm[2][64 * 128]; // 2x16KB [e][k],  swz ((e&15)<<4)

    const int tid = threadIdx.x;
    const int lane = tid & 63;
    const int w = tid >> 6;       // 0..15
    const int eg = w & 1;         // edge group: rows eg*32..+32
    const int cg = w >> 1;        // col group:  cols cg*16..+16

    // stage W once (r10-proven conflict-free map)
    {
        const int icol = tid & 127, seg = tid >> 7;
        const ushort_t* src = wbf + icol * 512 + seg * 64;
#pragma unroll
        for (int m = 0; m < 8; m++) {
            const s16x8 v = *(const s16x8*)(src + m * 8);
            const int byte = icol * 1024 + ((seg * 128 + m * 16) ^ ((icol & 15) << 4));
            *(s16x8*)((char*)Bsm + byte) = v;
        }
    }
    const int icol = cg * 16 + (lane & 15);
    const float bias_r = bias[icol];

    const f32x4 zero = {0.f, 0.f, 0.f, 0.f};
    const int ntiles = NE / 64;
    const int stride = gridDim.x;

    auto STAGE = [&](int tt, int b) {
        const int rr = w * 4 + (lane >> 4);
        const int col = ei[NE + tt * 64 + rr];
        const int c = (lane & 15) ^ (rr & 15);
        const ushort_t* src = xbf + (size_t)col * 128 + c * 8;
        __builtin_amdgcn_global_load_lds(
            (const __attribute__((address_space(1))) unsigned int*)src,
            (__attribute__((address_space(3))) unsigned int*)((char*)Asm[b] + w * 1024),
            16, 0, 0);
    };

    int t = blockIdx.x;
    int cur = 0;
    if (t < ntiles) STAGE(t, 0);

#pragma unroll 1
    for (; t < ntiles; t += stride) {
        __syncthreads();
        const int tn = t + stride;
        if (tn < ntiles) STAGE(tn, cur ^ 1);

        const f32x4 alp = *(const f32x4*)(alpha4 + (size_t)(t * 64 + eg * 32 + (lane & 31)) * 4);

        s16x8 af[2][4];
#pragma unroll
        for (int eb = 0; eb < 2; eb++) {
            const int rr = eg * 32 + eb * 16 + (lane & 15);
#pragma unroll
            for (int ks = 0; ks < 4; ks++) {
                const int byte = rr * 256 + ((ks * 64 + (lane >> 4) * 16) ^ ((rr & 15) << 4));
                af[eb][ks] = *(const s16x8*)((const char*)Asm[cur] + byte);
            }
        }

        f32x4 fin[2];
        fin[0] = zero; fin[1] = zero;

#pragma unroll
        for (int h = 0; h < 4; h++) {
            s16x8 bfr[4];
#pragma unroll
            for (int ks = 0; ks < 4; ks++) {
                const int byte = icol * 1024 +
                    ((h * 256 + ks * 64 + (lane >> 4) * 16) ^ ((icol & 15) << 4));
                bfr[ks] = *(const s16x8*)((const char*)Bsm + byte);
            }
#pragma unroll
            for (int eb = 0; eb < 2; eb++) {
                f32x4 a = __builtin_amdgcn_mfma_f32_16x16x32_bf16(af[eb][0], bfr[0], zero, 0, 0, 0);
#pragma unroll
                for (int ks = 1; ks < 4; ks++)
                    a = __builtin_amdgcn_mfma_f32_16x16x32_bf16(af[eb][ks], bfr[ks], a, 0, 0, 0);
                f32x4 av;
#pragma unroll
                for (int r = 0; r < 4; r++)
                    av[r] = __shfl(alp[h], eb * 16 + (lane >> 4) * 4 + r, 64);
                fin[eb] += av * a;
            }
        }
        // epilogue: + bias + residual; nt out stores (write-once data)
#pragma unroll
        for (int eb = 0; eb < 2; eb++) {
#pragma unroll
            for (int r = 0; r < 4; r++) {
                const int e = t * 64 + eg * 32 + eb * 16 + (lane >> 4) * 4 + r;
                const size_t off = (size_t)e * 128 + icol;
                __builtin_nontemporal_store(fin[eb][r] + bias_r + bf2f(xbf[off]), &out[off]);
            }
        }
        cur ^= 1;
    }
}

extern "C" void kernel_launch(void* const* d_in, const int* in_sizes, int n_in,
                              void* d_out, int out_size, void* d_ws, size_t ws_size,
                              hipStream_t stream) {
    const float* x      = (const float*)d_in[0];
    const int*   ei_raw = (const int*)d_in[1];
    const float* att    = (const float*)d_in[2];
    const float* W      = (const float*)d_in[3];
    const float* b      = (const float*)d_in[4];
    float* out = (float*)d_out;

    char* ws = (char*)d_ws;
    float*    uv      = (float*)(ws);                     // N*8 f32   = 12.8 MB
    float*    p       = (float*)(ws + 12800000);          // E*4 f32   =  6.4 MB
    float*    denom   = (float*)(ws + 19200000);          // N*4 f32   =  6.4 MB
    float*    alpha4  = (float*)(ws + 25600000);          // E*4 f32   =  6.4 MB
    ushort_t* wbf     = (ushort_t*)(ws + 32000000);       // 128 KB
    int*      flag    = (int*)(ws + 32200000);            // 4 B
    ushort_t* attB    = (ushort_t*)(ws + 32200064);       // 4 KB
    int*      ei32    = (int*)(ws + 32210048);            // 3.2 MB
    ushort_t* xbf     = (ushort_t*)(ws + 35420224);       // N*128 bf16 = 102.4 MB

    // denom zeroing folded into k_prep blocks 258.. (was hipMemsetAsync: the
    // rocclr fill kernel cost 112-117 µs/replay as the first replay node)
    k_prep<<<258 + (NN + 255) / 256, 256, 0, stream>>>(W, wbf, att, attB, ei_raw, flag, denom);
    k_uv_mfma<<<2048, 256, 0, stream>>>(x, attB, xbf, uv);
    k_edge<<<(NE + 255) / 256, 256, 0, stream>>>(ei_raw, flag, uv, p, denom, ei32);
    k_alpha<<<(NE + 255) / 256, 256, 0, stream>>>(ei32, p, denom, alpha4);
    k_gemm<<<256, 1024, 0, stream>>>(xbf, ei32, alpha4, wbf, b, out);
}

// Round 21
// 257.437 us; speedup vs baseline: 1.0907x; 1.0324x over previous
//
#include <hip/hip_runtime.h>

#define NN 400000
#define NE 400000

typedef __attribute__((ext_vector_type(4))) float f32x4;
typedef __attribute__((ext_vector_type(8))) short s16x8;
typedef unsigned short ushort_t;

__device__ __forceinline__ ushort_t f2bf(float f) {
    union { float f; unsigned int u; } c;
    c.f = f;
    unsigned int u = c.u;
    u = u + 0x7fffu + ((u >> 16) & 1u);
    return (ushort_t)(u >> 16);
}
__device__ __forceinline__ float bf2f(ushort_t v) {
    union { unsigned int u; float f; } c;
    c.u = ((unsigned int)v) << 16;
    return c.f;
}

// --- merged prep: blocks 0..255 W->bf16; block 256 attB; block 257 int64 detect;
//     blocks 258.. zero denom ---
__global__ void k_prep(const float* __restrict__ W, ushort_t* __restrict__ wbf,
                       const float* __restrict__ att, ushort_t* __restrict__ attB,
                       const int* __restrict__ ei_raw, int* __restrict__ flag,
                       float* __restrict__ denom) {
    if (blockIdx.x < 256) {
        const int i = blockIdx.x * 256 + threadIdx.x;
        wbf[i] = f2bf(W[i]);
    } else if (blockIdx.x == 256) {
        const int t = threadIdx.x;          // 256
        const int ks = t >> 6, lane = t & 63;
        const int col = lane & 15, kg = lane >> 4;
        const int jb = ks * 32 + kg * 8;
        s16x8 pk;
#pragma unroll
        for (int m = 0; m < 8; m++) {
            float v = 0.f;
            if (col < 4)      v = att[col * 256 + jb + m];
            else if (col < 8) v = att[(col - 4) * 256 + 128 + jb + m];
            pk[m] = (short)f2bf(v);
        }
        *(s16x8*)(attB + (size_t)(ks * 64 + lane) * 8) = pk;
    } else if (blockIdx.x == 257) {
        if (threadIdx.x < 64) {
            const int v = ei_raw[2 * threadIdx.x + 1];
            const unsigned long long b = __ballot(v != 0);
            if (threadIdx.x == 0) flag[0] = (b == 0ULL) ? 1 : 0;
        }
    } else {
        const int i = (blockIdx.x - 258) * 256 + threadIdx.x;
        if (i < NN) *(f32x4*)(denom + (size_t)i * 4) = (f32x4){0.f, 0.f, 0.f, 0.f};
    }
}

// --- fused u,v + x->bf16, MFMA + nt x loads (r18/19-proven) ---
__global__ __launch_bounds__(256) void k_uv_mfma(
    const float* __restrict__ x, const ushort_t* __restrict__ attB,
    ushort_t* __restrict__ xbf, float* __restrict__ uv) {
    const int lane = threadIdx.x & 63;
    const int wv = threadIdx.x >> 6;     // 4 waves/block
    const int kg = lane >> 4;

    s16x8 bfr[4];
#pragma unroll
    for (int ks = 0; ks < 4; ks++)
        bfr[ks] = *(const s16x8*)(attB + (size_t)(ks * 64 + lane) * 8);

    const f32x4 zero = {0.f, 0.f, 0.f, 0.f};
    const int ntiles = NN / 64;

#pragma unroll 1
    for (int tile = blockIdx.x; tile < ntiles; tile += gridDim.x) {
        const int n = tile * 64 + wv * 16 + (lane & 15);
        const float* xr = x + (size_t)n * 128 + kg * 8;
        ushort_t* xw = xbf + (size_t)n * 128 + kg * 8;

        s16x8 afr[4];
#pragma unroll
        for (int ks = 0; ks < 4; ks++) {
            const f32x4 a0 = __builtin_nontemporal_load((const f32x4*)(xr + ks * 32));
            const f32x4 a1 = __builtin_nontemporal_load((const f32x4*)(xr + ks * 32 + 4));
            s16x8 pk;
#pragma unroll
            for (int m = 0; m < 4; m++) { pk[m] = (short)f2bf(a0[m]); pk[4 + m] = (short)f2bf(a1[m]); }
            afr[ks] = pk;
            *(s16x8*)(xw + ks * 32) = pk;    // xbf output (same bytes as A-frag)
        }
        f32x4 c = zero;
#pragma unroll
        for (int ks = 0; ks < 4; ks++)
            c = __builtin_amdgcn_mfma_f32_16x16x32_bf16(afr[ks], bfr[ks], c, 0, 0, 0);

        const int colc = lane & 15;
        if (colc < 8) {
#pragma unroll
            for (int r = 0; r < 4; r++) {
                const int nn = tile * 64 + wv * 16 + kg * 4 + r;
                uv[(size_t)nn * 8 + colc] = c[r];
            }
        }
    }
}

// --- per-edge (fused idx-convert): leaky_relu -> head softmax -> p=exp, atomic
//     denom; also emits ei32 ---
__global__ void k_edge(const int* __restrict__ ei_raw, const int* __restrict__ flag,
                       const float* __restrict__ uv, float* __restrict__ p,
                       float* __restrict__ denom, int* __restrict__ ei32) {
    const int e = blockIdx.x * 256 + threadIdx.x;
    if (e >= NE) return;
    const int f = flag[0];
    const int row = f ? ei_raw[2 * e] : ei_raw[e];
    const int col = f ? ei_raw[2 * (NE + e)] : ei_raw[NE + e];
    ei32[e] = row;
    ei32[NE + e] = col;
    const f32x4 u = *(const f32x4*)(uv + (size_t)row * 8);
    const f32x4 v = *(const f32x4*)(uv + (size_t)col * 8 + 4);
    float s[4];
    float mx = -1e30f;
#pragma unroll
    for (int h = 0; h < 4; h++) {
        float t = u[h] + v[h];
        t = t > 0.f ? t : 0.01f * t;
        s[h] = t;
        mx = fmaxf(mx, t);
    }
    float ex[4], sum = 0.f;
#pragma unroll
    for (int h = 0; h < 4; h++) { ex[h] = __expf(s[h] - mx); sum += ex[h]; }
    const float inv = 1.f / sum;
    f32x4 pv;
#pragma unroll
    for (int h = 0; h < 4; h++) pv[h] = __expf(ex[h] * inv);
    *(f32x4*)(p + (size_t)e * 4) = pv;
#pragma unroll
    for (int h = 0; h < 4; h++) atomicAdd(denom + (size_t)row * 4 + h, pv[h]);
}

// --- alpha4[e] = p[e,:] / denom[row[e],:] ---
__global__ void k_alpha(const int* __restrict__ ei, const float* __restrict__ p,
                        const float* __restrict__ denom, float* __restrict__ alpha4) {
    const int e = blockIdx.x * 256 + threadIdx.x;
    if (e >= NE) return;
    const int row = ei[e];
    const f32x4 pv = *(const f32x4*)(p + (size_t)e * 4);
    const f32x4 dv = *(const f32x4*)(denom + (size_t)row * 4);
    *(f32x4*)(alpha4 + (size_t)e * 4) = pv / dv;
}

// --- persistent head-split GEMM, v13: 8 waves (512 thr), B in 64 VGPR/wave.
//     LDS-pipe budget/tile was 7.7k cyc (384 ds_read_b128 + 512 bpermute);
//     wave now owns its 16 cols' W frags in REGISTERS (loaded from Bsm once —
//     ds_reads are NOT rematerializable, unlike the r5-r7 global-load trap).
//     Per-tile LDS ops drop to 128 af-reads + 512 bp ≈ 4.6k cyc.
//     512 thr -> launch_bounds(512,2) -> 256-VGPR cap, ~130 live. Wave covers
//     all 64 tile-edges (eb 0..3); lane holds edge (t*64+lane)'s alpha. ---
__global__ __launch_bounds__(512, 2) void k_gemm(
    const ushort_t* __restrict__ xbf, const int* __restrict__ ei,
    const float* __restrict__ alpha4, const ushort_t* __restrict__ wbf,
    const float* __restrict__ bias, float* __restrict__ out)
{
    __shared__ __align__(16) ushort_t Bsm[128 * 512];   // 128KB [icol][k], swz ((icol&15)<<4)
    __shared__ __align__(16) ushort_t Asm[2][64 * 128]; // 2x16KB [e][k],  swz ((e&15)<<4)

    const int tid = threadIdx.x;
    const int lane = tid & 63;
    const int w = tid >> 6;       // 0..7; wave owns cols w*16..+16
    const int kg = lane >> 4;

    // stage W once: icol = tid>>2 (0..127), quarter q = tid&3 (256B), swz (icol&15)
    {
        const int icol = tid >> 2, q = tid & 3;
        const ushort_t* src = wbf + icol * 512 + q * 128;
#pragma unroll
        for (int m = 0; m < 16; m++) {
            const s16x8 v = *(const s16x8*)(src + m * 8);
            const int byte = icol * 1024 + ((q * 256 + m * 16) ^ ((icol & 15) << 4));
            *(s16x8*)((char*)Bsm + byte) = v;
        }
    }
    const int icol = w * 16 + (lane & 15);
    const float bias_r = bias[icol];

    const f32x4 zero = {0.f, 0.f, 0.f, 0.f};
    const int ntiles = NE / 64;
    const int stride = gridDim.x;

    // async A stage: 2 global_load_lds per thread (512 thr x 2 x 16B = 16KB)
    auto STAGE = [&](int tt, int b) {
#pragma unroll
        for (int i = 0; i < 2; i++) {
            const int rr = w * 8 + i * 4 + (lane >> 4);
            const int col = ei[NE + tt * 64 + rr];
            const int c = (lane & 15) ^ (rr & 15);
            const ushort_t* src = xbf + (size_t)col * 128 + c * 8;
            __builtin_amdgcn_global_load_lds(
                (const __attribute__((address_space(1))) unsigned int*)src,
                (__attribute__((address_space(3))) unsigned int*)((char*)Asm[b] + w * 2048 + i * 1024),
                16, 0, 0);
        }
    };

    int t = blockIdx.x;
    int cur = 0;
    if (t < ntiles) STAGE(t, 0);
    __syncthreads();   // W staged + first A landed

    // B fragments: held in 64 VGPR for the whole kernel (LDS reads can't remat)
    s16x8 bfr[4][4];
#pragma unroll
    for (int h = 0; h < 4; h++)
#pragma unroll
        for (int ks = 0; ks < 4; ks++) {
            const int byte = icol * 1024 +
                ((h * 256 + ks * 64 + kg * 16) ^ ((icol & 15) << 4));
            bfr[h][ks] = *(const s16x8*)((const char*)Bsm + byte);
        }

#pragma unroll 1
    for (; t < ntiles; t += stride) {
        const int tn = t + stride;
        if (tn < ntiles) STAGE(tn, cur ^ 1);   // in flight under this tile's compute

        // alpha: lane holds edge (t*64+lane), coalesced f32x4
        const f32x4 alp = *(const f32x4*)(alpha4 + (size_t)(t * 64 + lane) * 4);

#pragma unroll
        for (int eb = 0; eb < 4; eb++) {
            // A fragment for this 16-edge block
            s16x8 af[4];
            const int rr = eb * 16 + (lane & 15);
#pragma unroll
            for (int ks = 0; ks < 4; ks++) {
                const int byte = rr * 256 + ((ks * 64 + kg * 16) ^ ((rr & 15) << 4));
                af[ks] = *(const s16x8*)((const char*)Asm[cur] + byte);
            }
            f32x4 fin = zero;
#pragma unroll
            for (int h = 0; h < 4; h++) {
                f32x4 a = __builtin_amdgcn_mfma_f32_16x16x32_bf16(af[0], bfr[h][0], zero, 0, 0, 0);
#pragma unroll
                for (int ks = 1; ks < 4; ks++)
                    a = __builtin_amdgcn_mfma_f32_16x16x32_bf16(af[ks], bfr[h][ks], a, 0, 0, 0);
                f32x4 av;
#pragma unroll
                for (int r = 0; r < 4; r++)
                    av[r] = __shfl(alp[h], eb * 16 + kg * 4 + r, 64);
                fin += av * a;
            }
            // epilogue: + bias + residual; nt out stores
#pragma unroll
            for (int r = 0; r < 4; r++) {
                const int e = t * 64 + eb * 16 + kg * 4 + r;
                const size_t off = (size_t)e * 128 + icol;
                __builtin_nontemporal_store(fin[r] + bias_r + bf2f(xbf[off]), &out[off]);
            }
        }
        __syncthreads();   // drains STAGE(cur^1); all waves done with Asm[cur]
        cur ^= 1;
    }
}

extern "C" void kernel_launch(void* const* d_in, const int* in_sizes, int n_in,
                              void* d_out, int out_size, void* d_ws, size_t ws_size,
                              hipStream_t stream) {
    const float* x      = (const float*)d_in[0];
    const int*   ei_raw = (const int*)d_in[1];
    const float* att    = (const float*)d_in[2];
    const float* W      = (const float*)d_in[3];
    const float* b      = (const float*)d_in[4];
    float* out = (float*)d_out;

    char* ws = (char*)d_ws;
    float*    uv      = (float*)(ws);                     // N*8 f32   = 12.8 MB
    float*    p       = (float*)(ws + 12800000);          // E*4 f32   =  6.4 MB
    float*    denom   = (float*)(ws + 19200000);          // N*4 f32   =  6.4 MB
    float*    alpha4  = (float*)(ws + 25600000);          // E*4 f32   =  6.4 MB
    ushort_t* wbf     = (ushort_t*)(ws + 32000000);       // 128 KB
    int*      flag    = (int*)(ws + 32200000);            // 4 B
    ushort_t* attB    = (ushort_t*)(ws + 32200064);       // 4 KB
    int*      ei32    = (int*)(ws + 32210048);            // 3.2 MB
    ushort_t* xbf     = (ushort_t*)(ws + 35420224);       // N*128 bf16 = 102.4 MB

    k_prep<<<258 + (NN + 255) / 256, 256, 0, stream>>>(W, wbf, att, attB, ei_raw, flag, denom);
    k_uv_mfma<<<2048, 256, 0, stream>>>(x, attB, xbf, uv);
    k_edge<<<(NE + 255) / 256, 256, 0, stream>>>(ei_raw, flag, uv, p, denom, ei32);
    k_alpha<<<(NE + 255) / 256, 256, 0, stream>>>(ei32, p, denom, alpha4);
    k_gemm<<<256, 512, 0, stream>>>(xbf, ei32, alpha4, wbf, b, out);
}

// Round 22
// 254.654 us; speedup vs baseline: 1.1026x; 1.0109x over previous
//
#include <hip/hip_runtime.h>

#define NN 400000
#define NE 400000

typedef __attribute__((ext_vector_type(4))) float f32x4;
typedef __attribute__((ext_vector_type(8))) short s16x8;
typedef unsigned short ushort_t;

__device__ __forceinline__ ushort_t f2bf(float f) {
    union { float f; unsigned int u; } c;
    c.f = f;
    unsigned int u = c.u;
    u = u + 0x7fffu + ((u >> 16) & 1u);
    return (ushort_t)(u >> 16);
}
__device__ __forceinline__ float bf2f(ushort_t v) {
    union { unsigned int u; float f; } c;
    c.u = ((unsigned int)v) << 16;
    return c.f;
}
__device__ __forceinline__ float bits2f(unsigned u) {
    union { unsigned u; float f; } c;
    c.u = u;
    return c.f;
}

// --- merged prep: blocks 0..255 W->bf16; block 256 attB; block 257 int64 detect;
//     blocks 258.. zero denom ---
__global__ void k_prep(const float* __restrict__ W, ushort_t* __restrict__ wbf,
                       const float* __restrict__ att, ushort_t* __restrict__ attB,
                       const int* __restrict__ ei_raw, int* __restrict__ flag,
                       float* __restrict__ denom) {
    if (blockIdx.x < 256) {
        const int i = blockIdx.x * 256 + threadIdx.x;
        wbf[i] = f2bf(W[i]);
    } else if (blockIdx.x == 256) {
        const int t = threadIdx.x;          // 256
        const int ks = t >> 6, lane = t & 63;
        const int col = lane & 15, kg = lane >> 4;
        const int jb = ks * 32 + kg * 8;
        s16x8 pk;
#pragma unroll
        for (int m = 0; m < 8; m++) {
            float v = 0.f;
            if (col < 4)      v = att[col * 256 + jb + m];
            else if (col < 8) v = att[(col - 4) * 256 + 128 + jb + m];
            pk[m] = (short)f2bf(v);
        }
        *(s16x8*)(attB + (size_t)(ks * 64 + lane) * 8) = pk;
    } else if (blockIdx.x == 257) {
        if (threadIdx.x < 64) {
            const int v = ei_raw[2 * threadIdx.x + 1];
            const unsigned long long b = __ballot(v != 0);
            if (threadIdx.x == 0) flag[0] = (b == 0ULL) ? 1 : 0;
        }
    } else {
        const int i = (blockIdx.x - 258) * 256 + threadIdx.x;
        if (i < NN) *(f32x4*)(denom + (size_t)i * 4) = (f32x4){0.f, 0.f, 0.f, 0.f};
    }
}

// --- fused u,v + x->bf16, MFMA + nt x loads (r18/19-proven) ---
__global__ __launch_bounds__(256) void k_uv_mfma(
    const float* __restrict__ x, const ushort_t* __restrict__ attB,
    ushort_t* __restrict__ xbf, float* __restrict__ uv) {
    const int lane = threadIdx.x & 63;
    const int wv = threadIdx.x >> 6;     // 4 waves/block
    const int kg = lane >> 4;

    s16x8 bfr[4];
#pragma unroll
    for (int ks = 0; ks < 4; ks++)
        bfr[ks] = *(const s16x8*)(attB + (size_t)(ks * 64 + lane) * 8);

    const f32x4 zero = {0.f, 0.f, 0.f, 0.f};
    const int ntiles = NN / 64;

#pragma unroll 1
    for (int tile = blockIdx.x; tile < ntiles; tile += gridDim.x) {
        const int n = tile * 64 + wv * 16 + (lane & 15);
        const float* xr = x + (size_t)n * 128 + kg * 8;
        ushort_t* xw = xbf + (size_t)n * 128 + kg * 8;

        s16x8 afr[4];
#pragma unroll
        for (int ks = 0; ks < 4; ks++) {
            const f32x4 a0 = __builtin_nontemporal_load((const f32x4*)(xr + ks * 32));
            const f32x4 a1 = __builtin_nontemporal_load((const f32x4*)(xr + ks * 32 + 4));
            s16x8 pk;
#pragma unroll
            for (int m = 0; m < 4; m++) { pk[m] = (short)f2bf(a0[m]); pk[4 + m] = (short)f2bf(a1[m]); }
            afr[ks] = pk;
            *(s16x8*)(xw + ks * 32) = pk;    // xbf output (same bytes as A-frag)
        }
        f32x4 c = zero;
#pragma unroll
        for (int ks = 0; ks < 4; ks++)
            c = __builtin_amdgcn_mfma_f32_16x16x32_bf16(afr[ks], bfr[ks], c, 0, 0, 0);

        const int colc = lane & 15;
        if (colc < 8) {
#pragma unroll
            for (int r = 0; r < 4; r++) {
                const int nn = tile * 64 + wv * 16 + kg * 4 + r;
                uv[(size_t)nn * 8 + colc] = c[r];
            }
        }
    }
}

// --- per-edge (fused idx-convert): leaky_relu -> head softmax -> p=exp, atomic
//     denom; also emits ei32 ---
__global__ void k_edge(const int* __restrict__ ei_raw, const int* __restrict__ flag,
                       const float* __restrict__ uv, float* __restrict__ p,
                       float* __restrict__ denom, int* __restrict__ ei32) {
    const int e = blockIdx.x * 256 + threadIdx.x;
    if (e >= NE) return;
    const int f = flag[0];
    const int row = f ? ei_raw[2 * e] : ei_raw[e];
    const int col = f ? ei_raw[2 * (NE + e)] : ei_raw[NE + e];
    ei32[e] = row;
    ei32[NE + e] = col;
    const f32x4 u = *(const f32x4*)(uv + (size_t)row * 8);
    const f32x4 v = *(const f32x4*)(uv + (size_t)col * 8 + 4);
    float s[4];
    float mx = -1e30f;
#pragma unroll
    for (int h = 0; h < 4; h++) {
        float t = u[h] + v[h];
        t = t > 0.f ? t : 0.01f * t;
        s[h] = t;
        mx = fmaxf(mx, t);
    }
    float ex[4], sum = 0.f;
#pragma unroll
    for (int h = 0; h < 4; h++) { ex[h] = __expf(s[h] - mx); sum += ex[h]; }
    const float inv = 1.f / sum;
    f32x4 pv;
#pragma unroll
    for (int h = 0; h < 4; h++) pv[h] = __expf(ex[h] * inv);
    *(f32x4*)(p + (size_t)e * 4) = pv;
#pragma unroll
    for (int h = 0; h < 4; h++) atomicAdd(denom + (size_t)row * 4 + h, pv[h]);
}

// --- alpha4[e] = p[e,:] / denom[row[e],:] ---
__global__ void k_alpha(const int* __restrict__ ei, const float* __restrict__ p,
                        const float* __restrict__ denom, float* __restrict__ alpha4) {
    const int e = blockIdx.x * 256 + threadIdx.x;
    if (e >= NE) return;
    const int row = ei[e];
    const f32x4 pv = *(const f32x4*)(p + (size_t)e * 4);
    const f32x4 dv = *(const f32x4*)(denom + (size_t)row * 4);
    *(f32x4*)(alpha4 + (size_t)e * 4) = pv / dv;
}

// --- persistent head-split GEMM, v14 = v13 + PACKED-BF16 alpha shuffles.
//     v13's LDS pipe/tile: 128 ds_read_b128 (af) + 512 ds_bpermute (alpha).
//     Pack alpha[0..3] into 2 bf16-pair words -> 8 shuffles/eb (was 16),
//     halving bpermutes (512->256/tile). Unpack = 1 bit-op per (h,r) on the
//     idle VALU. alpha rel-err 2^-9 adds ~0.004 abs — negligible. ---
__global__ __launch_bounds__(512, 2) void k_gemm(
    const ushort_t* __restrict__ xbf, const int* __restrict__ ei,
    const float* __restrict__ alpha4, const ushort_t* __restrict__ wbf,
    const float* __restrict__ bias, float* __restrict__ out)
{
    __shared__ __align__(16) ushort_t Bsm[128 * 512];   // 128KB [icol][k], swz ((icol&15)<<4)
    __shared__ __align__(16) ushort_t Asm[2][64 * 128]; // 2x16KB [e][k],  swz ((e&15)<<4)

    const int tid = threadIdx.x;
    const int lane = tid & 63;
    const int w = tid >> 6;       // 0..7; wave owns cols w*16..+16
    const int kg = lane >> 4;

    // stage W once: icol = tid>>2 (0..127), quarter q = tid&3 (256B), swz (icol&15)
    {
        const int icol = tid >> 2, q = tid & 3;
        const ushort_t* src = wbf + icol * 512 + q * 128;
#pragma unroll
        for (int m = 0; m < 16; m++) {
            const s16x8 v = *(const s16x8*)(src + m * 8);
            const int byte = icol * 1024 + ((q * 256 + m * 16) ^ ((icol & 15) << 4));
            *(s16x8*)((char*)Bsm + byte) = v;
        }
    }
    const int icol = w * 16 + (lane & 15);
    const float bias_r = bias[icol];

    const f32x4 zero = {0.f, 0.f, 0.f, 0.f};
    const int ntiles = NE / 64;
    const int stride = gridDim.x;

    // async A stage: 2 global_load_lds per thread (512 thr x 2 x 16B = 16KB)
    auto STAGE = [&](int tt, int b) {
#pragma unroll
        for (int i = 0; i < 2; i++) {
            const int rr = w * 8 + i * 4 + (lane >> 4);
            const int col = ei[NE + tt * 64 + rr];
            const int c = (lane & 15) ^ (rr & 15);
            const ushort_t* src = xbf + (size_t)col * 128 + c * 8;
            __builtin_amdgcn_global_load_lds(
                (const __attribute__((address_space(1))) unsigned int*)src,
                (__attribute__((address_space(3))) unsigned int*)((char*)Asm[b] + w * 2048 + i * 1024),
                16, 0, 0);
        }
    };

    int t = blockIdx.x;
    int cur = 0;
    if (t < ntiles) STAGE(t, 0);
    __syncthreads();   // W staged + first A landed

    // B fragments: held in 64 VGPR for the whole kernel (LDS reads can't remat)
    s16x8 bfr[4][4];
#pragma unroll
    for (int h = 0; h < 4; h++)
#pragma unroll
        for (int ks = 0; ks < 4; ks++) {
            const int byte = icol * 1024 +
                ((h * 256 + ks * 64 + kg * 16) ^ ((icol & 15) << 4));
            bfr[h][ks] = *(const s16x8*)((const char*)Bsm + byte);
        }

#pragma unroll 1
    for (; t < ntiles; t += stride) {
        const int tn = t + stride;
        if (tn < ntiles) STAGE(tn, cur ^ 1);   // in flight under this tile's compute

        // alpha: lane holds edge (t*64+lane); pack 4 f32 -> 2 bf16-pair words
        const f32x4 alp = *(const f32x4*)(alpha4 + (size_t)(t * 64 + lane) * 4);
        const int p01 = (int)((unsigned)f2bf(alp[0]) | ((unsigned)f2bf(alp[1]) << 16));
        const int p23 = (int)((unsigned)f2bf(alp[2]) | ((unsigned)f2bf(alp[3]) << 16));

#pragma unroll
        for (int eb = 0; eb < 4; eb++) {
            // A fragment for this 16-edge block
            s16x8 af[4];
            const int rr = eb * 16 + (lane & 15);
#pragma unroll
            for (int ks = 0; ks < 4; ks++) {
                const int byte = rr * 256 + ((ks * 64 + kg * 16) ^ ((rr & 15) << 4));
                af[ks] = *(const s16x8*)((const char*)Asm[cur] + byte);
            }
            // packed alpha shuffles: 8 per eb (was 16 f32 shuffles)
            int u01[4], u23[4];
#pragma unroll
            for (int r = 0; r < 4; r++) {
                const int src = eb * 16 + kg * 4 + r;
                u01[r] = __shfl(p01, src, 64);
                u23[r] = __shfl(p23, src, 64);
            }
            f32x4 fin = zero;
#pragma unroll
            for (int h = 0; h < 4; h++) {
                f32x4 a = __builtin_amdgcn_mfma_f32_16x16x32_bf16(af[0], bfr[h][0], zero, 0, 0, 0);
#pragma unroll
                for (int ks = 1; ks < 4; ks++)
                    a = __builtin_amdgcn_mfma_f32_16x16x32_bf16(af[ks], bfr[h][ks], a, 0, 0, 0);
#pragma unroll
                for (int r = 0; r < 4; r++) {
                    const unsigned uw = (unsigned)((h < 2) ? u01[r] : u23[r]);
                    const unsigned bits = (h & 1) ? (uw & 0xffff0000u) : (uw << 16);
                    fin[r] += bits2f(bits) * a[r];
                }
            }
            // epilogue: + bias + residual; nt out stores
#pragma unroll
            for (int r = 0; r < 4; r++) {
                const int e = t * 64 + eb * 16 + kg * 4 + r;
                const size_t off = (size_t)e * 128 + icol;
                __builtin_nontemporal_store(fin[r] + bias_r + bf2f(xbf[off]), &out[off]);
            }
        }
        __syncthreads();   // drains STAGE(cur^1); all waves done with Asm[cur]
        cur ^= 1;
    }
}

extern "C" void kernel_launch(void* const* d_in, const int* in_sizes, int n_in,
                              void* d_out, int out_size, void* d_ws, size_t ws_size,
                              hipStream_t stream) {
    const float* x      = (const float*)d_in[0];
    const int*   ei_raw = (const int*)d_in[1];
    const float* att    = (const float*)d_in[2];
    const float* W      = (const float*)d_in[3];
    const float* b      = (const float*)d_in[4];
    float* out = (float*)d_out;

    char* ws = (char*)d_ws;
    float*    uv      = (float*)(ws);                     // N*8 f32   = 12.8 MB
    float*    p       = (float*)(ws + 12800000);          // E*4 f32   =  6.4 MB
    float*    denom   = (float*)(ws + 19200000);          // N*4 f32   =  6.4 MB
    float*    alpha4  = (float*)(ws + 25600000);          // E*4 f32   =  6.4 MB
    ushort_t* wbf     = (ushort_t*)(ws + 32000000);       // 128 KB
    int*      flag    = (int*)(ws + 32200000);            // 4 B
    ushort_t* attB    = (ushort_t*)(ws + 32200064);       // 4 KB
    int*      ei32    = (int*)(ws + 32210048);            // 3.2 MB
    ushort_t* xbf     = (ushort_t*)(ws + 35420224);       // N*128 bf16 = 102.4 MB

    k_prep<<<258 + (NN + 255) / 256, 256, 0, stream>>>(W, wbf, att, attB, ei_raw, flag, denom);
    k_uv_mfma<<<2048, 256, 0, stream>>>(x, attB, xbf, uv);
    k_edge<<<(NE + 255) / 256, 256, 0, stream>>>(ei_raw, flag, uv, p, denom, ei32);
    k_alpha<<<(NE + 255) / 256, 256, 0, stream>>>(ei32, p, denom, alpha4);
    k_gemm<<<256, 512, 0, stream>>>(xbf, ei32, alpha4, wbf, b, out);
}